// Round 5
// baseline (636.925 us; speedup 1.0000x reference)
//
#include <hip/hip_runtime.h>
#include <stdint.h>

static constexpr int CI = 16;
static constexpr int CO = 32;
static constexpr int H  = 300000;
static constexpr int K  = 27;
static constexpr float BN_EPS = 1e-5f;

// ---------- bf16 helpers ----------
__device__ __forceinline__ unsigned short f2bf(float f) {
    union { float f; unsigned int i; } v; v.f = f;
    unsigned int x = v.i;
    return (unsigned short)((x + 0x7fffu + ((x >> 16) & 1u)) >> 16);  // RNE
}
// one word -> two floats, 2 VALU ops total (lshl + and)
__device__ __forceinline__ void unpack2(unsigned int u, float& lo, float& hi) {
    union { unsigned int i; float f; } a, b;
    a.i = u << 16;
    b.i = u & 0xffff0000u;
    lo = a.f; hi = b.f;
}

// ---------- kernel 1: fused prep ----------
// x fp32 (CI,H) -> xT bf16 (H,CI);  w fp32 (o,i,k) -> wf[k][o*CI+i];  zero stats[64]
__global__ __launch_bounds__(256) void prep(const float* __restrict__ x,
                                            const float* __restrict__ w,
                                            unsigned short* __restrict__ xT,
                                            float* __restrict__ wf,
                                            float* __restrict__ stats) {
    int h = blockIdx.x * 256 + threadIdx.x;
    if (h < H) {
        union { unsigned short s[CI]; uint4 q[2]; } v;
        #pragma unroll
        for (int i = 0; i < CI; ++i) v.s[i] = f2bf(x[(size_t)i * H + h]);  // coalesced per i
        uint4* dst = reinterpret_cast<uint4*>(xT + (size_t)h * CI);
        dst[0] = v.q[0];
        dst[1] = v.q[1];
    }
    if (blockIdx.x == 0) {
        for (int t = threadIdx.x; t < CO * CI * K; t += 256) {
            int k  = t % K;
            int oi = t / K;                 // oi = o*CI + i (source is (o,i,k) flat)
            wf[k * (CO * CI) + oi] = w[t];
        }
        if (threadIdx.x < 64) stats[threadIdx.x] = 0.f;   // gsum[32] ++ gsq[32]
    }
}

// ---------- kernel 2: gathered conv, software-pipelined, + fused BN stats ----------
__global__ __launch_bounds__(256) void conv(const unsigned short* __restrict__ xT,
                                            const float* __restrict__ wf,
                                            const int* __restrict__ neigh,
                                            float* __restrict__ out,
                                            float* __restrict__ stats) {
    __shared__ int snb[256 * K];
    const int h = blockIdx.x * 256 + threadIdx.x;

    // stage this block's neighbor indices coalesced into LDS
    {
        const int base = blockIdx.x * 256 * K;
        for (int t = threadIdx.x; t < 256 * K; t += 256) {
            int g = base + t;
            snb[t] = (g < H * K) ? neigh[g] : -1;
        }
    }
    __syncthreads();

    float acc[CO];
    #pragma unroll
    for (int o = 0; o < CO; ++o) acc[o] = 0.f;

    if (h < H) {
        const int* np = &snb[threadIdx.x * K];

        // prologue: prefetch k = 0
        int idx = np[0];
        const uint4* p0 = reinterpret_cast<const uint4*>(
            xT + (size_t)(idx < 0 ? 0 : idx) * CI);
        uint4 a = p0[0];
        uint4 b = p0[1];

        for (int k = 0; k < K; ++k) {
            // issue next gather before consuming current (latency hidden by 512 FMAs)
            const int nidx = (k + 1 < K) ? np[k + 1] : 0;
            const uint4* p1 = reinterpret_cast<const uint4*>(
                xT + (size_t)(nidx < 0 ? 0 : nidx) * CI);
            uint4 na = p1[0];
            uint4 nb = p1[1];

            // zero-mask invalid neighbor (cndmask, no divergence in practice)
            if (idx < 0) {
                a.x = a.y = a.z = a.w = 0u;
                b.x = b.y = b.z = b.w = 0u;
            }
            float xi[CI];
            unpack2(a.x, xi[0],  xi[1]);  unpack2(a.y, xi[2],  xi[3]);
            unpack2(a.z, xi[4],  xi[5]);  unpack2(a.w, xi[6],  xi[7]);
            unpack2(b.x, xi[8],  xi[9]);  unpack2(b.y, xi[10], xi[11]);
            unpack2(b.z, xi[12], xi[13]); unpack2(b.w, xi[14], xi[15]);

            const float* wk = wf + k * (CO * CI);   // wave-uniform -> scalar loads
            #pragma unroll
            for (int o = 0; o < CO; ++o) {
                float s = acc[o];
                #pragma unroll
                for (int i = 0; i < CI; ++i) s = fmaf(wk[o * CI + i], xi[i], s);
                acc[o] = s;
            }

            idx = nidx; a = na; b = nb;
        }
        #pragma unroll
        for (int o = 0; o < CO; ++o) out[(size_t)o * H + h] = acc[o];  // fp32 out
    }

    // fused BN statistics: 64-lane butterfly per channel, one atomic per wave/channel
    const unsigned lane = threadIdx.x & 63u;
    float mySum = 0.f, mySq = 0.f;
    #pragma unroll
    for (int o = 0; o < CO; ++o) {
        float v = acc[o];
        float q = v * v;
        #pragma unroll
        for (int d = 32; d > 0; d >>= 1) {
            v += __shfl_xor(v, d, 64);
            q += __shfl_xor(q, d, 64);
        }
        if (lane == (unsigned)o) { mySum = v; mySq = q; }
    }
    if (lane < CO) {
        atomicAdd(&stats[lane], mySum);        // gsum
        atomicAdd(&stats[32 + lane], mySq);    // gsq
    }
}

// ---------- kernel 3: BN apply (scale/shift recomputed per thread from stats) ----------
__global__ __launch_bounds__(256) void bn_apply(float* __restrict__ out,
                                                const float* __restrict__ stats,
                                                const float* __restrict__ gamma,
                                                const float* __restrict__ beta) {
    size_t t = (size_t)blockIdx.x * 256 + threadIdx.x;
    size_t base = t * 4;
    if (base >= (size_t)CO * H) return;
    int o = (int)(base / (size_t)H);     // H % 4 == 0 -> float4 never crosses channels
    const float invH = 1.f / (float)H;
    float m   = stats[o] * invH;
    float var = stats[32 + o] * invH - m * m;
    float inv = rsqrtf(var + BN_EPS);
    float sc  = gamma[o] * inv;
    float sh  = beta[o] - m * sc;
    float4* p = reinterpret_cast<float4*>(out + base);
    float4 q = *p;
    q.x = q.x * sc + sh;
    q.y = q.y * sc + sh;
    q.z = q.z * sc + sh;
    q.w = q.w * sc + sh;
    *p = q;
}

// ---------- launch ----------
extern "C" void kernel_launch(void* const* d_in, const int* in_sizes, int n_in,
                              void* d_out, int out_size, void* d_ws, size_t ws_size,
                              hipStream_t stream) {
    const float* x     = (const float*)d_in[0];   // fp32 (1,CI,H,1)
    const float* w     = (const float*)d_in[1];   // fp32 (CO,CI,K)
    const float* gamma = (const float*)d_in[2];   // fp32 (CO)
    const float* beta  = (const float*)d_in[3];   // fp32 (CO)
    const int*   neigh = (const int*)d_in[4];     // int32 (H,K)
    float*       out   = (float*)d_out;           // fp32 (CO,H)

    char* ws = (char*)d_ws;
    const size_t XT_OFF    = 0;                    // H*CI*2    = 9,600,000 B
    const size_t WF_OFF    = 9600000;              // CO*CI*K*4 = 55,296 B
    const size_t STATS_OFF = 9655296;              // 64 floats
    unsigned short* xT    = (unsigned short*)(ws + XT_OFF);
    float*          wf    = (float*)(ws + WF_OFF);
    float*          stats = (float*)(ws + STATS_OFF);

    const int HB = (H + 255) / 256;                // 1172
    prep<<<HB, 256, 0, stream>>>(x, w, xT, wf, stats);
    conv<<<HB, 256, 0, stream>>>(xT, wf, neigh, out, stats);

    const int NBN = (CO * H / 4 + 255) / 256;      // 9375
    bn_apply<<<NBN, 256, 0, stream>>>(out, stats, gamma, beta);
}

// Round 6
// 446.962 us; speedup vs baseline: 1.4250x; 1.4250x over previous
//
#include <hip/hip_runtime.h>
#include <stdint.h>

static constexpr int CI = 16;
static constexpr int CO = 32;
static constexpr int H  = 300000;
static constexpr int K  = 27;
static constexpr float BN_EPS = 1e-5f;

// ---------- bf16 helpers ----------
__device__ __forceinline__ unsigned short f2bf(float f) {
    union { float f; unsigned int i; } v; v.f = f;
    unsigned int x = v.i;
    return (unsigned short)((x + 0x7fffu + ((x >> 16) & 1u)) >> 16);  // RNE
}
// one word -> two floats, 2 VALU ops (lshl + and)
__device__ __forceinline__ void unpack2(unsigned int u, float& lo, float& hi) {
    union { unsigned int i; float f; } a, b;
    a.i = u << 16;
    b.i = u & 0xffff0000u;
    lo = a.f; hi = b.f;
}

// ---------- kernel 1: fused prep ----------
// x fp32 (CI,H) -> xT bf16 (H,CI);  w fp32 (o,i,k) -> wf[k][o*CI+i];  zero stats[64]
__global__ __launch_bounds__(256) void prep(const float* __restrict__ x,
                                            const float* __restrict__ w,
                                            unsigned short* __restrict__ xT,
                                            float* __restrict__ wf,
                                            float* __restrict__ stats) {
    int h = blockIdx.x * 256 + threadIdx.x;
    if (h < H) {
        union { unsigned short s[CI]; uint4 q[2]; } v;
        #pragma unroll
        for (int i = 0; i < CI; ++i) v.s[i] = f2bf(x[(size_t)i * H + h]);  // coalesced per i
        uint4* dst = reinterpret_cast<uint4*>(xT + (size_t)h * CI);
        dst[0] = v.q[0];
        dst[1] = v.q[1];
    }
    if (blockIdx.x == 0) {
        for (int t = threadIdx.x; t < CO * CI * K; t += 256) {
            int k  = t % K;
            int oi = t / K;                 // oi = o*CI + i (source is (o,i,k) flat)
            wf[k * (CO * CI) + oi] = w[t];
        }
        if (threadIdx.x < 64) stats[threadIdx.x] = 0.f;   // gsum[32] ++ gsq[32]
    }
}

// ---------- kernel 2: gathered conv, CO split across wave-pairs, + fused BN stats ----------
// Block: 256 threads = 128 h. Waves 0-1 (t<128): outputs 0-15. Waves 2-3: outputs 16-31.
// half is wave-uniform (readfirstlane) -> weight loads stay scalar (s_load).
// acc[16] + xi[16] + 2 row buffers ~= 56 VGPR -> no spill, high occupancy.
__global__ __launch_bounds__(256) void conv(const unsigned short* __restrict__ xT,
                                            const float* __restrict__ wf,
                                            const int* __restrict__ neigh,
                                            float* __restrict__ out,
                                            float* __restrict__ stats) {
    __shared__ int snb[128 * K];
    const int t  = threadIdx.x;
    const int hl = t & 127;
    const int half = __builtin_amdgcn_readfirstlane(t >> 7);   // 0 or 1, wave-uniform
    const int h  = blockIdx.x * 128 + hl;

    // stage this block's neighbor indices coalesced into LDS
    {
        const int base = blockIdx.x * 128 * K;
        for (int s = t; s < 128 * K; s += 256) {
            int g = base + s;
            snb[s] = (g < H * K) ? neigh[g] : -1;
        }
    }
    __syncthreads();

    float acc[16];
    #pragma unroll
    for (int o = 0; o < 16; ++o) acc[o] = 0.f;

    if (h < H) {
        const int* np = &snb[hl * K];
        const float* wh = wf + half * (16 * CI);   // this wave's output-half within each k-block

        // prologue: prefetch k = 0
        int idx = np[0];
        const uint4* p0 = reinterpret_cast<const uint4*>(
            xT + (size_t)(idx < 0 ? 0 : idx) * CI);
        uint4 a = p0[0];
        uint4 b = p0[1];

        for (int k = 0; k < K; ++k) {
            const int nidx = (k + 1 < K) ? np[k + 1] : 0;
            const uint4* p1 = reinterpret_cast<const uint4*>(
                xT + (size_t)(nidx < 0 ? 0 : nidx) * CI);
            uint4 na = p1[0];
            uint4 nb = p1[1];

            if (idx < 0) {                      // cndmask zero for invalid neighbor
                a.x = a.y = a.z = a.w = 0u;
                b.x = b.y = b.z = b.w = 0u;
            }
            float xi[CI];
            unpack2(a.x, xi[0],  xi[1]);  unpack2(a.y, xi[2],  xi[3]);
            unpack2(a.z, xi[4],  xi[5]);  unpack2(a.w, xi[6],  xi[7]);
            unpack2(b.x, xi[8],  xi[9]);  unpack2(b.y, xi[10], xi[11]);
            unpack2(b.z, xi[12], xi[13]); unpack2(b.w, xi[14], xi[15]);

            const float* wk = wh + k * (CO * CI);   // wave-uniform -> scalar loads
            #pragma unroll
            for (int o = 0; o < 16; ++o) {
                float s = acc[o];
                #pragma unroll
                for (int i = 0; i < CI; ++i) s = fmaf(wk[o * CI + i], xi[i], s);
                acc[o] = s;
            }

            idx = nidx; a = na; b = nb;
        }
        #pragma unroll
        for (int o = 0; o < 16; ++o)
            out[(size_t)(half * 16 + o) * H + h] = acc[o];   // coalesced over h
    }

    // fused BN statistics: butterfly per output, one atomic per wave per output
    const unsigned lane = t & 63u;
    float mySum = 0.f, mySq = 0.f;
    #pragma unroll
    for (int o = 0; o < 16; ++o) {
        float v = acc[o];
        float q = v * v;
        #pragma unroll
        for (int d = 32; d > 0; d >>= 1) {
            v += __shfl_xor(v, d, 64);
            q += __shfl_xor(q, d, 64);
        }
        if (lane == (unsigned)o) { mySum = v; mySq = q; }
    }
    if (lane < 16u) {
        atomicAdd(&stats[half * 16 + lane], mySum);        // gsum
        atomicAdd(&stats[32 + half * 16 + lane], mySq);    // gsq
    }
}

// ---------- kernel 3: BN apply (scale/shift recomputed per thread from stats) ----------
__global__ __launch_bounds__(256) void bn_apply(float* __restrict__ out,
                                                const float* __restrict__ stats,
                                                const float* __restrict__ gamma,
                                                const float* __restrict__ beta) {
    size_t t = (size_t)blockIdx.x * 256 + threadIdx.x;
    size_t base = t * 4;
    if (base >= (size_t)CO * H) return;
    int o = (int)(base / (size_t)H);     // H % 4 == 0 -> float4 never crosses channels
    const float invH = 1.f / (float)H;
    float m   = stats[o] * invH;
    float var = stats[32 + o] * invH - m * m;
    float inv = rsqrtf(var + BN_EPS);
    float sc  = gamma[o] * inv;
    float sh  = beta[o] - m * sc;
    float4* p = reinterpret_cast<float4*>(out + base);
    float4 q = *p;
    q.x = q.x * sc + sh;
    q.y = q.y * sc + sh;
    q.z = q.z * sc + sh;
    q.w = q.w * sc + sh;
    *p = q;
}

// ---------- launch ----------
extern "C" void kernel_launch(void* const* d_in, const int* in_sizes, int n_in,
                              void* d_out, int out_size, void* d_ws, size_t ws_size,
                              hipStream_t stream) {
    const float* x     = (const float*)d_in[0];   // fp32 (1,CI,H,1)
    const float* w     = (const float*)d_in[1];   // fp32 (CO,CI,K)
    const float* gamma = (const float*)d_in[2];   // fp32 (CO)
    const float* beta  = (const float*)d_in[3];   // fp32 (CO)
    const int*   neigh = (const int*)d_in[4];     // int32 (H,K)
    float*       out   = (float*)d_out;           // fp32 (CO,H)

    char* ws = (char*)d_ws;
    const size_t XT_OFF    = 0;                    // H*CI*2    = 9,600,000 B
    const size_t WF_OFF    = 9600000;              // CO*CI*K*4 = 55,296 B
    const size_t STATS_OFF = 9655296;              // 64 floats
    unsigned short* xT    = (unsigned short*)(ws + XT_OFF);
    float*          wf    = (float*)(ws + WF_OFF);
    float*          stats = (float*)(ws + STATS_OFF);

    const int HBP = (H + 255) / 256;               // 1172 (prep)
    prep<<<HBP, 256, 0, stream>>>(x, w, xT, wf, stats);

    const int HBC = (H + 127) / 128;               // 2344 (conv: 128 h/block)
    conv<<<HBC, 256, 0, stream>>>(xT, wf, neigh, out, stats);

    const int NBN = (CO * H / 4 + 255) / 256;      // 9375
    bn_apply<<<NBN, 256, 0, stream>>>(out, stats, gamma, beta);
}